// Round 13
// baseline (907.804 us; speedup 1.0000x reference)
//
#include <hip/hip_runtime.h>
#include <hip/hip_bf16.h>
#include <stdint.h>

typedef long long ll;
typedef unsigned short ushort_t;
typedef __attribute__((ext_vector_type(8))) short bf16x8;
typedef __attribute__((ext_vector_type(4))) float f32x4;

static inline int cdiv_ll(ll a, int b) { return (int)((a + (ll)b - 1) / (ll)b); }

#define BIN_SHIFT 9
#define BIN_SIZE 512
#define KMAX 1536         // max buckets (M2 <= 768K)
#define CHUNK 8192        // records per workgroup in binning passes
#define RPT (CHUNK / 256) // records per thread (32)

// ---------------- dtype detection (bf16 vs fp32 inputs) ----------------
__global__ void k_detect(const unsigned int* __restrict__ dw, const ll n_dw, int* __restrict__ flag) {
    __shared__ int sc[256];
    int tid = threadIdx.x;
    int cnt = 0;
    for (int s = 0; s < 32; s++) {
        ll idx = (ll)(s * 256 + tid);
        ll i = (idx * n_dw) / 8192;
        unsigned v = dw[i];
        unsigned lo = v & 0xFFFFu;
        unsigned ex = (lo >> 7) & 0xFFu;
        bool pl = (lo == 0u) || (lo == 0x8000u) || (ex >= 0x60u && ex <= 0x8Fu);
        cnt += pl ? 1 : 0;
    }
    sc[tid] = cnt;
    __syncthreads();
    for (int o = 128; o > 0; o >>= 1) { if (tid < o) sc[tid] += sc[tid + o]; __syncthreads(); }
    if (tid == 0) *flag = (sc[0] * 2 > 8192) ? 1 : 0;
}

__device__ __forceinline__ float load_in(const void* p, ll i, int isbf16) {
    if (isbf16) return __bfloat162float(((const __hip_bfloat16*)p)[i]);
    return ((const float*)p)[i];
}

__device__ __forceinline__ float bf2f(ushort_t u) {
    return __uint_as_float(((unsigned)u) << 16);
}
__device__ __forceinline__ ushort_t f2bf(float f) {
    unsigned u = __float_as_uint(f);
    unsigned r = (u + 0x7FFFu + ((u >> 16) & 1u)) >> 16;
    return (ushort_t)r;
}

// ---------------- fused weight conversion ----------------
__global__ void k_cvt_weights(const void* __restrict__ W1u, const void* __restrict__ b1u,
                              const void* __restrict__ w2u, const void* __restrict__ W1i,
                              const void* __restrict__ b1i, const void* __restrict__ w2i,
                              ushort_t* __restrict__ Wbu, float* __restrict__ fb1u,
                              float* __restrict__ fw2u, ushort_t* __restrict__ Wbi,
                              float* __restrict__ fb1i, float* __restrict__ fw2i,
                              const int* __restrict__ flag) {
    int i = blockIdx.x * blockDim.x + threadIdx.x;
    int bf = *flag;
    const int WSZ = 64 * 128;
    if (i < WSZ) {
        int d = i >> 7, h = i & 127;
        Wbu[h * 64 + d] = f2bf(load_in(W1u, i, bf));
    } else if (i < WSZ + 128) {
        fb1u[i - WSZ] = load_in(b1u, i - WSZ, bf);
    } else if (i < WSZ + 256) {
        fw2u[i - WSZ - 128] = load_in(w2u, i - WSZ - 128, bf);
    } else if (i < 2 * WSZ + 256) {
        int j = i - WSZ - 256;
        int d = j >> 7, h = j & 127;
        Wbi[h * 64 + d] = f2bf(load_in(W1i, j, bf));
    } else if (i < 2 * WSZ + 384) {
        fb1i[i - 2 * WSZ - 256] = load_in(b1i, i - 2 * WSZ - 256, bf);
    } else if (i < 2 * WSZ + 512) {
        fw2i[i - 2 * WSZ - 384] = load_in(w2i, i - 2 * WSZ - 384, bf);
    }
}

// ---------------- record decode ----------------
__device__ __forceinline__ void decode_rec(ll t,
    const int* __restrict__ uiR, const int* __restrict__ uiC,
    const int* __restrict__ u1s, const int* __restrict__ u1d,
    const int* __restrict__ u2s, const int* __restrict__ u2d,
    const int* __restrict__ i1s, const int* __restrict__ i1d,
    const int* __restrict__ i2s, const int* __restrict__ i2d,
    const ll E2, const ll EU1, const ll EU2, const ll EI1, const ll EI2,
    const int N, const int U, const int I, const int M,
    int& key, int& col) {
    if (t < E2) { key = uiR[t]; col = uiC[t]; return; }
    t -= E2;
    if (t < EU1) { key = N + u1d[t]; col = u1s[t]; return; }
    t -= EU1;
    if (t < EU1) { key = M + u1s[t]; col = 0; return; }
    t -= EU1;
    if (t < EU2) { key = N + U + u2d[t]; col = u2s[t]; return; }
    t -= EU2;
    if (t < EU2) { key = M + U + u2s[t]; col = 0; return; }
    t -= EU2;
    if (t < EI1) { key = N + 2 * U + i1d[t]; col = i1s[t]; return; }
    t -= EI1;
    if (t < EI1) { key = M + 2 * U + i1s[t]; col = 0; return; }
    t -= EI1;
    if (t < EI2) { key = N + 2 * U + I + i2d[t]; col = i2s[t]; return; }
    t -= EI2;
    key = M + 2 * U + I + i2s[t]; col = 0;
}

// key-only decode (histogram pass never needs col)
__device__ __forceinline__ int decode_key(ll t,
    const int* __restrict__ uiR,
    const int* __restrict__ u1s, const int* __restrict__ u1d,
    const int* __restrict__ u2s, const int* __restrict__ u2d,
    const int* __restrict__ i1s, const int* __restrict__ i1d,
    const int* __restrict__ i2s, const int* __restrict__ i2d,
    const ll E2, const ll EU1, const ll EU2, const ll EI1, const ll EI2,
    const int N, const int U, const int I, const int M) {
    if (t < E2) return uiR[t];
    t -= E2;
    if (t < EU1) return N + u1d[t];
    t -= EU1;
    if (t < EU1) return M + u1s[t];
    t -= EU1;
    if (t < EU2) return N + U + u2d[t];
    t -= EU2;
    if (t < EU2) return M + U + u2s[t];
    t -= EU2;
    if (t < EI1) return N + 2 * U + i1d[t];
    t -= EI1;
    if (t < EI1) return M + 2 * U + i1s[t];
    t -= EI1;
    if (t < EI2) return N + 2 * U + I + i2d[t];
    t -= EI2;
    return M + 2 * U + I + i2s[t];
}

#define DECODE_ARGS uiR, uiC, u1s, u1d, u2s, u2d, i1s, i1d, i2s, i2d, \
                    E2, EU1, EU2, EI1, EI2, N, U, I, M

// ---------------- pass A1: per-WG LDS histogram -> global bucket totals ----
__global__ __launch_bounds__(256) void kA_hist(
    const int* __restrict__ uiR,
    const int* __restrict__ u1s, const int* __restrict__ u1d,
    const int* __restrict__ u2s, const int* __restrict__ u2d,
    const int* __restrict__ i1s, const int* __restrict__ i1d,
    const int* __restrict__ i2s, const int* __restrict__ i2d,
    const ll E2, const ll EU1, const ll EU2, const ll EI1, const ll EI2,
    const int N, const int U, const int I, const int M,
    const ll RT, const int K, int* __restrict__ btot /* K*32 line-padded */) {
    __shared__ int hist[KMAX];
    for (int i = threadIdx.x; i < K; i += 256) hist[i] = 0;
    __syncthreads();
    ll base = (ll)blockIdx.x * CHUNK;
#pragma unroll
    for (int i = 0; i < RPT; i++) {
        ll t = base + i * 256 + threadIdx.x;
        if (t < RT) {
            int key = decode_key(t, uiR, u1s, u1d, u2s, u2d, i1s, i1d, i2s, i2d,
                                 E2, EU1, EU2, EI1, EI2, N, U, I, M);
            atomicAdd(&hist[key >> BIN_SHIFT], 1);
        }
    }
    __syncthreads();
    for (int k = threadIdx.x; k < K; k += 256)
        if (hist[k]) atomicAdd(&btot[k * 32], hist[k]);
}

// ---------------- bucket scan: totals -> bases, init cursors ----------------
__global__ __launch_bounds__(1024) void k_bscan(const int* __restrict__ btot,
                                                int* __restrict__ bbase,
                                                int* __restrict__ bcursor, const int K) {
    __shared__ int sh[1024];
    __shared__ int carry;
    int t = threadIdx.x;
    if (t == 0) carry = 0;
    __syncthreads();
    for (int base = 0; base < K; base += 1024) {
        int idx = base + t;
        int v = (idx < K) ? btot[idx * 32] : 0;
        sh[t] = v;
        __syncthreads();
        for (int off = 1; off < 1024; off <<= 1) {
            int x = (t >= off) ? sh[t - off] : 0;
            __syncthreads();
            sh[t] += x;
            __syncthreads();
        }
        if (idx < K) {
            int ex = carry + sh[t] - v;
            bbase[idx] = ex;
            bcursor[idx * 32] = ex;
        }
        __syncthreads();
        if (t == 0) carry += sh[1023];
        __syncthreads();
    }
}

// ---------------- pass A2: scatter, single decode (register stash) ----------
__global__ __launch_bounds__(256) void kA_scatter(
    const int* __restrict__ uiR, const int* __restrict__ uiC,
    const int* __restrict__ u1s, const int* __restrict__ u1d,
    const int* __restrict__ u2s, const int* __restrict__ u2d,
    const int* __restrict__ i1s, const int* __restrict__ i1d,
    const int* __restrict__ i2s, const int* __restrict__ i2d,
    const ll E2, const ll EU1, const ll EU2, const ll EI1, const ll EI2,
    const int N, const int U, const int I, const int M,
    const ll RT, const int K, int* __restrict__ bcursor, int2* __restrict__ binned) {
    __shared__ int hist[KMAX];
    __shared__ int lcur[KMAX];
    int keyArr[RPT];
    int colArr[RPT];
    for (int i = threadIdx.x; i < K; i += 256) hist[i] = 0;
    __syncthreads();
    ll base = (ll)blockIdx.x * CHUNK;
#pragma unroll
    for (int i = 0; i < RPT; i++) {
        ll t = base + i * 256 + threadIdx.x;
        int key = -1, col = 0;
        if (t < RT) {
            decode_rec(t, DECODE_ARGS, key, col);
            atomicAdd(&hist[key >> BIN_SHIFT], 1);
        }
        keyArr[i] = key;
        colArr[i] = col;
    }
    __syncthreads();
    for (int k = threadIdx.x; k < K; k += 256) {
        int h = hist[k];
        lcur[k] = h ? atomicAdd(&bcursor[k * 32], h) : 0;
    }
    __syncthreads();
#pragma unroll
    for (int i = 0; i < RPT; i++) {
        int key = keyArr[i];
        if (key >= 0) {
            int pos = atomicAdd(&lcur[key >> BIN_SHIFT], 1);
            binned[pos] = make_int2(key, colArr[i]);
        }
    }
}

// ---------------- pass B1: per-bucket LDS count -> counts array ----------
__global__ __launch_bounds__(256) void kB1_count(const int2* __restrict__ binned,
                                                 const int* __restrict__ bbase,
                                                 const int* __restrict__ btot,
                                                 int* __restrict__ counts, const int M2) {
    __shared__ int cnt[BIN_SIZE];
    int b = blockIdx.x;
    int lo = b << BIN_SHIFT;
    int hi = min(lo + BIN_SIZE, M2);
    for (int i = threadIdx.x; i < BIN_SIZE; i += 256) cnt[i] = 0;
    __syncthreads();
    int s = bbase[b], n = btot[b * 32];
    for (int j = s + threadIdx.x; j < s + n; j += 256) {
        atomicAdd(&cnt[binned[j].x - lo], 1);
    }
    __syncthreads();
    for (int i = threadIdx.x; i < hi - lo; i += 256) counts[lo + i] = cnt[i];
}

// ---------------- fused norms ----------------
__global__ void k_norm_all(const int* __restrict__ counts, float* __restrict__ nrm,
                           const int N, const int total) {
    int i = blockIdx.x * blockDim.x + threadIdx.x;
    if (i < total) {
        int c = counts[i];
        if (i < N) nrm[i] = (c > 0) ? (1.0f / sqrtf((float)c)) : 0.0f;
        else nrm[i] = 1.0f / sqrtf(fmaxf((float)c, 1.0f));
    }
}

// ---------------- hierarchical exclusive scan ----------
#define SCAN_T 256
#define SCAN_ELEMS 8
#define SCAN_CHUNK (SCAN_T * SCAN_ELEMS)   // 2048

__global__ __launch_bounds__(256) void k_scanA(const int* __restrict__ in, const int n,
                                               int* __restrict__ out, int* __restrict__ bsum) {
    __shared__ int sh[SCAN_T];
    int t = threadIdx.x;
    ll base = (ll)blockIdx.x * SCAN_CHUNK + (ll)t * SCAN_ELEMS;
    int v[SCAN_ELEMS];
    int tot = 0;
#pragma unroll
    for (int k = 0; k < SCAN_ELEMS; k++) {
        ll i = base + k;
        v[k] = (i < n) ? in[i] : 0;
        tot += v[k];
    }
    sh[t] = tot;
    __syncthreads();
    for (int off = 1; off < SCAN_T; off <<= 1) {
        int x = (t >= off) ? sh[t - off] : 0;
        __syncthreads();
        sh[t] += x;
        __syncthreads();
    }
    int run = sh[t] - tot;
#pragma unroll
    for (int k = 0; k < SCAN_ELEMS; k++) {
        ll i = base + k;
        if (i < n) out[i] = run;
        run += v[k];
    }
    if (t == SCAN_T - 1) bsum[blockIdx.x] = sh[SCAN_T - 1];
}

__global__ __launch_bounds__(256) void k_scanB(int* __restrict__ bsum, const int nb) {
    __shared__ int sh[256];
    int t = threadIdx.x;
    int running = 0;
    for (int base = 0; base < nb; base += 256) {
        int idx = base + t;
        int v = (idx < nb) ? bsum[idx] : 0;
        sh[t] = v;
        __syncthreads();
        for (int off = 1; off < 256; off <<= 1) {
            int x = (t >= off) ? sh[t - off] : 0;
            __syncthreads();
            sh[t] += x;
            __syncthreads();
        }
        if (idx < nb) bsum[idx] = running + sh[t] - v;
        int tot = sh[255];
        __syncthreads();
        running += tot;
    }
}

__global__ void k_scanC(int* __restrict__ S, const int n, const int* __restrict__ bsum, const int ET) {
    ll i = (ll)blockIdx.x * blockDim.x + threadIdx.x;
    if (i < n) S[i] += bsum[i / SCAN_CHUNK];
    if (i == 0) S[n] = ET;
}

// ---------------- pass B2: per-bucket CSR fill via LDS cursors ----------
__global__ __launch_bounds__(256) void kB2_fill(const int2* __restrict__ binned,
                                                const int* __restrict__ bbase,
                                                const int* __restrict__ btot,
                                                const int* __restrict__ S, const int M,
                                                int* __restrict__ ci_all) {
    __shared__ int scur[BIN_SIZE];
    int b = blockIdx.x;
    int lo = b << BIN_SHIFT;
    int hi = min(lo + BIN_SIZE, M);
    for (int i = threadIdx.x; i < hi - lo; i += 256) scur[i] = S[lo + i];
    __syncthreads();
    int s = bbase[b], n = btot[b * 32];
    for (int j = s + threadIdx.x; j < s + n; j += 256) {
        int2 rec = binned[j];
        if (rec.x < M) {
            int pos = atomicAdd(&scur[rec.x - lo], 1);
            ci_all[pos] = rec.y;
        }
    }
}

// ---------------- init features (bf16 storage) ----------------
__global__ void k_init(const void* __restrict__ uf, const void* __restrict__ itf,
                       ushort_t* __restrict__ ui, ushort_t* __restrict__ hu,
                       ushort_t* __restrict__ hi,
                       const ll nu64, const ll ntot64, const int* __restrict__ flag) {
    ll t = (ll)blockIdx.x * blockDim.x + threadIdx.x;
    int bf = *flag;
    if (t < nu64) {
        ushort_t v = bf ? ((const ushort_t*)uf)[t] : f2bf(((const float*)uf)[t]);
        ui[t] = v; hu[t] = v;
    } else if (t < ntot64) {
        ll j = t - nu64;
        ushort_t v = bf ? ((const ushort_t*)itf)[j] : f2bf(((const float*)itf)[j]);
        ui[t] = v; hi[j] = v;
    }
}

// ---------------- gather SpMM: 4 edge-slots x 16 dim-groups per wave ----------
// Lane = e4*16 + d16. Per iter the wave consumes 4 edges; each lane loads
// ushort4 (8 B = 4 dims) of its edge-slot's row -> 512 B per x-load inst.
// Epilogue: shfl-reduce across edge-slots, lanes 0..15 write the row.
__global__ __launch_bounds__(256) void k_gather(const int* __restrict__ row_ptr,
                                                const int* __restrict__ col_idx,
                                                const ushort_t* __restrict__ x,
                                                const float* __restrict__ cnorm,
                                                const float* __restrict__ rnorm,
                                                ushort_t* __restrict__ out, const int nrows) {
    ll gt = (ll)blockIdx.x * blockDim.x + threadIdx.x;
    int w = (int)(gt >> 6);
    if (w >= nrows) return;
    int lane = (int)(gt & 63);
    int e4 = lane >> 4;      // edge slot 0..3
    int d16 = lane & 15;     // dim group 0..15 (4 dims each)
    int s = row_ptr[w], e = row_ptr[w + 1];
    float a0 = 0.f, a1 = 0.f, a2 = 0.f, a3 = 0.f;
    for (int j = s; j < e; j += 4) {
        int jj = j + e4;
        bool v = jj < e;
        int c = col_idx[v ? jj : (e - 1)];
        float nm = v ? cnorm[c] : 0.0f;
        ushort4 xv = *(const ushort4*)&x[(ll)c * 64 + d16 * 4];
        a0 += bf2f(xv.x) * nm;
        a1 += bf2f(xv.y) * nm;
        a2 += bf2f(xv.z) * nm;
        a3 += bf2f(xv.w) * nm;
    }
    a0 += __shfl_down(a0, 32); a1 += __shfl_down(a1, 32);
    a2 += __shfl_down(a2, 32); a3 += __shfl_down(a3, 32);
    a0 += __shfl_down(a0, 16); a1 += __shfl_down(a1, 16);
    a2 += __shfl_down(a2, 16); a3 += __shfl_down(a3, 16);
    if (e4 == 0) {
        float rn = rnorm[w];
        ushort4 o;
        o.x = f2bf(a0 * rn); o.y = f2bf(a1 * rn);
        o.z = f2bf(a2 * rn); o.w = f2bf(a3 * rn);
        *(ushort4*)&out[(ll)w * 64 + d16 * 4] = o;
    }
}

// ---------------- fast tanh ----------
__device__ __forceinline__ float fast_tanh(float x) {
    return 1.0f - 2.0f / (__expf(2.0f * x) + 1.0f);
}

// ---------------- MFMA semantic-attention scores ----------------
__global__ __launch_bounds__(256) void k_attn_mfma(const ushort_t* __restrict__ z1,
                                                   const ushort_t* __restrict__ z2,
                                                   const ushort_t* __restrict__ Wb,
                                                   const float* __restrict__ b1f,
                                                   const float* __restrict__ w2f,
                                                   const int n, float* __restrict__ wsum) {
    __shared__ float red0[4], red1[4];
    int tid = threadIdx.x;
    int lane = tid & 63;
    int wid = tid >> 6;
    int col = lane & 15;
    int quad = lane >> 4;

    bf16x8 wb[8][2];
#pragma unroll
    for (int ht = 0; ht < 8; ht++) {
        int h = ht * 16 + col;
#pragma unroll
        for (int ks = 0; ks < 2; ks++) {
            wb[ht][ks] = *(const bf16x8*)&Wb[h * 64 + ks * 32 + quad * 8];
        }
    }
    float b1v[8], w2v[8];
#pragma unroll
    for (int ht = 0; ht < 8; ht++) {
        b1v[ht] = b1f[ht * 16 + col];
        w2v[ht] = w2f[ht * 16 + col];
    }

    float w0 = 0.0f, w1 = 0.0f;
    int ntiles = (n + 15) >> 4;
    int gw = blockIdx.x * 4 + wid;
    int nw = gridDim.x * 4;
    const bf16x8 zero8 = {0, 0, 0, 0, 0, 0, 0, 0};

    for (int tile = gw; tile < ntiles; tile += nw) {
        int nodeA = tile * 16 + col;
        bool va = nodeA < n;
        bf16x8 a1[2], a2[2];
#pragma unroll
        for (int ks = 0; ks < 2; ks++) {
            const bf16x8* p1 = (const bf16x8*)&z1[(ll)nodeA * 64 + ks * 32 + quad * 8];
            const bf16x8* p2 = (const bf16x8*)&z2[(ll)nodeA * 64 + ks * 32 + quad * 8];
            a1[ks] = va ? p1[0] : zero8;
            a2[ks] = va ? p2[0] : zero8;
        }
#pragma unroll
        for (int ht = 0; ht < 8; ht++) {
            f32x4 c1 = {0.f, 0.f, 0.f, 0.f};
            f32x4 c2 = {0.f, 0.f, 0.f, 0.f};
            c1 = __builtin_amdgcn_mfma_f32_16x16x32_bf16(a1[0], wb[ht][0], c1, 0, 0, 0);
            c1 = __builtin_amdgcn_mfma_f32_16x16x32_bf16(a1[1], wb[ht][1], c1, 0, 0, 0);
            c2 = __builtin_amdgcn_mfma_f32_16x16x32_bf16(a2[0], wb[ht][0], c2, 0, 0, 0);
            c2 = __builtin_amdgcn_mfma_f32_16x16x32_bf16(a2[1], wb[ht][1], c2, 0, 0, 0);
#pragma unroll
            for (int r = 0; r < 4; r++) {
                int node_row = tile * 16 + quad * 4 + r;
                bool vr = node_row < n;
                float t1 = fast_tanh(c1[r] + b1v[ht]) * w2v[ht];
                float t2 = fast_tanh(c2[r] + b1v[ht]) * w2v[ht];
                w0 += vr ? t1 : 0.0f;
                w1 += vr ? t2 : 0.0f;
            }
        }
    }

    for (int off = 32; off > 0; off >>= 1) {
        w0 += __shfl_down(w0, off);
        w1 += __shfl_down(w1, off);
    }
    if (lane == 0) { red0[wid] = w0; red1[wid] = w1; }
    __syncthreads();
    if (tid == 0) {
        atomicAdd(&wsum[0], red0[0] + red0[1] + red0[2] + red0[3]);
        atomicAdd(&wsum[1], red1[0] + red1[1] + red1[2] + red1[3]);
    }
}

// ---------------- combine with inline beta softmax (bf16 in/out) ----------
__global__ void k_combine(const ushort_t* __restrict__ z1, const ushort_t* __restrict__ z2,
                          const float* __restrict__ wsum, const float inv_n,
                          ushort_t* __restrict__ h, const ll n64) {
    ll t = (ll)blockIdx.x * blockDim.x + threadIdx.x;
    if (t < n64) {
        float m0 = wsum[0] * inv_n, m1 = wsum[1] * inv_n;
        float mx = fmaxf(m0, m1);
        float e0 = __expf(m0 - mx), e1 = __expf(m1 - mx);
        float inv_s = 1.0f / (e0 + e1);
        h[t] = f2bf((e0 * bf2f(z1[t]) + e1 * bf2f(z2[t])) * inv_s);
    }
}

// ---------------- fused output gather ----------------
__device__ __forceinline__ void store_out(void* out, ll i, float v, int isbf16) {
    if (isbf16) ((ushort_t*)out)[i] = f2bf(v);
    else ((float*)out)[i] = v;
}

__global__ void k_out(const ushort_t* __restrict__ hu, const ushort_t* __restrict__ hi,
                      const ushort_t* __restrict__ ui, const int* __restrict__ user_idx,
                      const int* __restrict__ item_idx, const int* __restrict__ neg_idx,
                      void* __restrict__ out, const int B, const ll U,
                      const int* __restrict__ flag) {
    ll t = (ll)blockIdx.x * blockDim.x + threadIdx.x;
    int bf = *flag;
    int d = (int)(t & 63);
    ll b = t >> 6;
    if (b < B) {
        int u = user_idx[b];
        float v = 0.5f * bf2f(hu[(ll)u * 64 + d]) + 0.5f * bf2f(ui[(ll)u * 64 + d]);
        store_out(out, b * 64 + d, v, bf);
    } else if (b < 2 * (ll)B) {
        ll bb = b - B;
        int it = item_idx[bb];
        float v = 0.5f * bf2f(hi[(ll)it * 64 + d]) + 0.5f * bf2f(ui[(U + it) * 64 + d]);
        store_out(out, (ll)B * 64 + bb * 64 + d, v, bf);
    } else if (b < 3 * (ll)B) {
        ll bb = b - 2 * (ll)B;
        int it = item_idx[neg_idx[bb]];
        float v = 0.5f * bf2f(hi[(ll)it * 64 + d]) + 0.5f * bf2f(ui[(U + it) * 64 + d]);
        store_out(out, (ll)2 * B * 64 + bb * 64 + d, v, bf);
    }
}

extern "C" void kernel_launch(void* const* d_in, const int* in_sizes, int n_in,
                              void* d_out, int out_size, void* d_ws, size_t ws_size,
                              hipStream_t stream) {
    const int D = 64;
    const ll U = in_sizes[0] / D;
    const ll I = in_sizes[1] / D;
    const ll N = U + I;
    const ll E2  = in_sizes[8] / 2;
    const ll EU1 = in_sizes[9] / 2;
    const ll EU2 = in_sizes[10] / 2;
    const ll EI1 = in_sizes[11] / 2;
    const ll EI2 = in_sizes[12] / 2;
    const ll ET = E2 + EU1 + EU2 + EI1 + EI2;
    const ll RT = E2 + 2 * (EU1 + EU2 + EI1 + EI2);   // binning records
    const int B = in_sizes[13];
    const int M = (int)(N + 2 * U + 2 * I);           // CSR/in-deg index space
    const int M2 = (int)(N + 4 * U + 4 * I);          // + out-deg space
    const int K = (M2 + BIN_SIZE - 1) >> BIN_SHIFT;   // buckets
    const int KM = (M + BIN_SIZE - 1) >> BIN_SHIFT;   // buckets covering [0,M)
    if (K > KMAX) return;

    const void* user_feat = d_in[0];
    const void* item_feat = d_in[1];
    const int* uiR = (const int*)d_in[8];
    const int* uiC = uiR + E2;
    const int* u1s = (const int*)d_in[9];
    const int* u1d = u1s + EU1;
    const int* u2s = (const int*)d_in[10];
    const int* u2d = u2s + EU2;
    const int* i1s = (const int*)d_in[11];
    const int* i1d = i1s + EI1;
    const int* i2s = (const int*)d_in[12];
    const int* i2d = i2s + EI2;
    const int* user_idx = (const int*)d_in[13];
    const int* item_idx = (const int*)d_in[14];
    const int* neg_idx  = (const int*)d_in[15];

    // ---------------- workspace layout ----------------
    ushort_t* q = (ushort_t*)d_ws;
    ushort_t* ui0 = q; q += N * 64;
    ushort_t* ui1 = q; q += N * 64;
    ushort_t* z1  = q; q += I * 64;
    ushort_t* z2  = q; q += I * 64;
    ushort_t* hu  = q; q += U * 64;
    ushort_t* hi  = q; q += I * 64;
    size_t feat_bytes = (size_t)(q - (ushort_t*)d_ws) * 2;
    if (feat_bytes < (size_t)RT * 8) return;   // binned overlay must fit
    int2* binned = (int2*)d_ws;

    float* p = (float*)(((uintptr_t)q + 15) & ~(uintptr_t)15);
    float* nrm = p;  p += M2;
    ushort_t* Wbu = (ushort_t*)p; p += 64 * 128 / 2;
    ushort_t* Wbi = (ushort_t*)p; p += 64 * 128 / 2;
    float* wb1u = p; p += 128;
    float* ww2u = p; p += 128;
    float* wb1i = p; p += 128;
    float* ww2i = p; p += 128;
    float* scratch = p; p += 16;

    int* ip = (int*)p;
    int* btot = ip;    ip += KMAX * 32;
    int* bbase = ip;   ip += KMAX;
    int* bcursor = ip; ip += KMAX * 32;
    int* counts = ip;  ip += M2;
    int* S = ip;       ip += M + 1;
    int* ci_all = ip;  ip += ET;
    int* bsum = ip;    ip += 256;
    int* flag = ip;    ip += 4;
    size_t needed = (size_t)((char*)ip - (char*)d_ws);
    if (ws_size < needed) return;

    const int T = 256;
    const int nWG_A = cdiv_ll(RT, CHUNK);

    // ---------------- dtype detection + weight conversion ----------------
    k_detect<<<1, 256, 0, stream>>>((const unsigned int*)user_feat, (ll)in_sizes[0] / 2, flag);
    k_cvt_weights<<<cdiv_ll(2 * (64 * 128 + 256), T), T, 0, stream>>>(
        d_in[2], d_in[3], d_in[4], d_in[5], d_in[6], d_in[7],
        Wbu, wb1u, ww2u, Wbi, wb1i, ww2i, flag);

    // ---------------- CSR build via 2-level binning ----------------
    hipMemsetAsync(btot, 0, (size_t)KMAX * 32 * sizeof(int), stream);
    hipMemsetAsync(scratch, 0, 16 * sizeof(float), stream);
    kA_hist<<<nWG_A, T, 0, stream>>>(uiR, u1s, u1d, u2s, u2d, i1s, i1d, i2s, i2d,
                                     E2, EU1, EU2, EI1, EI2, (int)N, (int)U, (int)I, M,
                                     RT, K, btot);
    k_bscan<<<1, 1024, 0, stream>>>(btot, bbase, bcursor, K);
    kA_scatter<<<nWG_A, T, 0, stream>>>(uiR, uiC, u1s, u1d, u2s, u2d, i1s, i1d, i2s, i2d,
                                        E2, EU1, EU2, EI1, EI2, (int)N, (int)U, (int)I, M,
                                        RT, K, bcursor, binned);
    kB1_count<<<K, T, 0, stream>>>(binned, bbase, btot, counts, M2);
    k_norm_all<<<cdiv_ll(M2, T), T, 0, stream>>>(counts, nrm, (int)N, M2);
    {
        int nb = (M + SCAN_CHUNK - 1) / SCAN_CHUNK;
        k_scanA<<<nb, SCAN_T, 0, stream>>>(counts, M, S, bsum);
        k_scanB<<<1, 256, 0, stream>>>(bsum, nb);
        k_scanC<<<cdiv_ll(M, T), T, 0, stream>>>(S, M, bsum, (int)ET);
    }
    kB2_fill<<<KM, T, 0, stream>>>(binned, bbase, btot, S, M, ci_all);

    // ---------------- init features (after binned is consumed) ----------------
    k_init<<<cdiv_ll(N * 64, T), T, 0, stream>>>(user_feat, item_feat, ui0, hu, hi, U * 64, N * 64, flag);

    // CSR segment row_ptr views
    const int* rp_ui = S;
    const int* rp_u1 = S + N;
    const int* rp_u2 = S + N + U;
    const int* rp_i1 = S + N + 2 * U;
    const int* rp_i2 = S + N + 2 * U + I;
    // norm views
    const float* dinv = nrm;
    const float* n_u1r = nrm + N;          const float* n_u2r = nrm + N + U;
    const float* n_i1r = nrm + N + 2 * U;  const float* n_i2r = nrm + N + 2 * U + I;
    const float* n_u1s = nrm + M;          const float* n_u2s = nrm + M + U;
    const float* n_i1s = nrm + M + 2 * U;  const float* n_i2s = nrm + M + 2 * U + I;

    ushort_t* uiA = ui0;
    ushort_t* uiB = ui1;
    const int ATTN_BLOCKS = 512;

    for (int layer = 0; layer < 2; layer++) {
        float* wsU = scratch + (layer ? 8 : 0);
        float* wsI = scratch + (layer ? 12 : 4);

        // ---- gcn_spmm ----
        k_gather<<<cdiv_ll(N * 64, T), T, 0, stream>>>(rp_ui, ci_all, uiA, dinv, dinv, uiB, (int)N);
        { ushort_t* tmp = uiA; uiA = uiB; uiB = tmp; }

        // ---- HAN: users ----
        k_gather<<<cdiv_ll(U * 64, T), T, 0, stream>>>(rp_u1, ci_all, hu, n_u1s, n_u1r, z1, (int)U);
        k_gather<<<cdiv_ll(U * 64, T), T, 0, stream>>>(rp_u2, ci_all, hu, n_u2s, n_u2r, z2, (int)U);
        k_attn_mfma<<<ATTN_BLOCKS, T, 0, stream>>>(z1, z2, Wbu, wb1u, ww2u, (int)U, wsU);
        k_combine<<<cdiv_ll(U * 64, T), T, 0, stream>>>(z1, z2, wsU, 1.0f / (float)U, hu, U * 64);

        // ---- HAN: items ----
        k_gather<<<cdiv_ll(I * 64, T), T, 0, stream>>>(rp_i1, ci_all, hi, n_i1s, n_i1r, z1, (int)I);
        k_gather<<<cdiv_ll(I * 64, T), T, 0, stream>>>(rp_i2, ci_all, hi, n_i2s, n_i2r, z2, (int)I);
        k_attn_mfma<<<ATTN_BLOCKS, T, 0, stream>>>(z1, z2, Wbi, wb1i, ww2i, (int)I, wsI);
        k_combine<<<cdiv_ll(I * 64, T), T, 0, stream>>>(z1, z2, wsI, 1.0f / (float)I, hi, I * 64);
    }

    // ---------------- final ----------------
    k_out<<<cdiv_ll((ll)3 * B * 64, T), T, 0, stream>>>(hu, hi, uiA, user_idx, item_idx, neg_idx,
                                                        d_out, B, U, flag);
}